// Round 22
// baseline (105.685 us; speedup 1.0000x reference)
//
#include <hip/hip_runtime.h>
#include <hip/hip_bf16.h>

// out[n,f] = weights[n] * ( x[n,:] . Wsum[f,:] + bsum[f] )
// Wsum = sum_e W[e], bsum = sum_e b[e]  (expert sum commutes with Linear).
// Wsum stored fragment-major ("Bfrag", R6) -> dense lane-consecutive B streams.
// R21: the untested combination. R6's shape (single 64-token tile, 64KB LDS ->
// TWO co-resident blocks/CU: 4 waves/SIMD hide ds_read->MFMA latency, block
// pair mixes read/compute/write phases at CU level) + R16's kloop (depth-3
// named-set B prefetch, sched_barrier(0) pinned). R6 had the shape but depth-1
// strangled-VGPR B; R16+ had the kloop but 1 block/CU. VGPR must stay <=128
// for dual residency -> __launch_bounds__(512,4).

#define N_TOK 32768
#define DIM   512
#define NEXP  8
#define BM    64            // tokens per block (single tile)

typedef __attribute__((ext_vector_type(8))) short  bf16x8;
typedef __attribute__((ext_vector_type(4))) float  f32x4;

__device__ __forceinline__ unsigned int pk2bf(float a, float b) {
    unsigned ua = __float_as_uint(a), ub = __float_as_uint(b);
    ua = (ua + 0x7FFFu + ((ua >> 16) & 1u)) >> 16;   // RNE to bf16
    ub = (ub + 0x7FFFu + ((ub >> 16) & 1u)) >> 16;
    return ua | (ub << 16);
}

// ---------------- prep: Bfrag (bf16, fragment-major) + bsum (f32) ---- (proven) ----
__global__ __launch_bounds__(64) void moe_prep(const float* __restrict__ W,
                                               const float* __restrict__ b,
                                               unsigned short* __restrict__ Bfrag,
                                               float* __restrict__ bsum) {
    const int g = blockIdx.x * 64 + threadIdx.x;     // 0..32767
    const int f = g >> 6;
    const int q = g & 63;
    const float* src = W + (size_t)f * DIM + q * 8;
    float s0 = 0, s1 = 0, s2 = 0, s3 = 0, s4 = 0, s5 = 0, s6 = 0, s7 = 0;
#pragma unroll
    for (int e = 0; e < NEXP; ++e) {
        float4 u0 = *(const float4*)(src + (size_t)e * DIM * DIM);
        float4 u1 = *(const float4*)(src + (size_t)e * DIM * DIM + 4);
        s0 += u0.x; s1 += u0.y; s2 += u0.z; s3 += u0.w;
        s4 += u1.x; s5 += u1.y; s6 += u1.z; s7 += u1.w;
    }
    uint4 v;
    v.x = pk2bf(s0, s1); v.y = pk2bf(s2, s3);
    v.z = pk2bf(s4, s5); v.w = pk2bf(s6, s7);

    const int F  = f >> 6, j = (f >> 4) & 3, lr = f & 15;
    const int sl = q >> 2, lg = q & 3;
    const int idx16 = ((F * 4 + j) * 16 + sl) * 64 + (lg * 16 + lr);
    *(uint4*)(Bfrag + (size_t)idx16 * 8) = v;

    if (g < DIM / 4) {
        float4 bs = make_float4(0.f, 0.f, 0.f, 0.f);
#pragma unroll
        for (int e = 0; e < NEXP; ++e) {
            float4 u = *(const float4*)(b + e * DIM + g * 4);
            bs.x += u.x; bs.y += u.y; bs.z += u.z; bs.w += u.w;
        }
        *(float4*)(bsum + g * 4) = bs;
    }
}

// ---- one granule: 8 f32 -> 16B bf16, XOR-swizzled LDS write (proven pair) ----
__device__ __forceinline__ void stage_granule(const float* __restrict__ srcrow,
                                              unsigned char* __restrict__ dstrow,
                                              int g, int row) {
    float4 u0 = *(const float4*)(srcrow + g * 8);
    float4 u1 = *(const float4*)(srcrow + g * 8 + 4);
    const int sg = (g & ~7) | ((g ^ row) & 7);
    uint4 v;
    v.x = pk2bf(u0.x, u0.y); v.y = pk2bf(u0.z, u0.w);
    v.z = pk2bf(u1.x, u1.y); v.w = pk2bf(u1.z, u1.w);
    *(uint4*)(dstrow + sg * 16) = v;
}

// ---------------- main GEMM: single tile, 2 blocks/CU, depth-3 pinned kloop ----------------
// Grid 512 (2 blocks/CU via 64KB LDS + VGPR<=128). Wave w owns features [w*64,(w+1)*64).
__global__ __launch_bounds__(512, 4) void moe_gemm(const float* __restrict__ x,
                                                   const float* __restrict__ wts,
                                                   const unsigned short* __restrict__ Bf,
                                                   const float* __restrict__ bsum,
                                                   float* __restrict__ out) {
    __shared__ __align__(16) unsigned char ldsA[BM * DIM * 2];   // 64 KB

    const int tid  = threadIdx.x;
    const int lane = tid & 63;
    const int w    = tid >> 6;       // 0..7
    const int lr   = lane & 15;
    const int lg   = lane >> 4;
    const int m0   = blockIdx.x * BM;
    const int f0   = w * 64;

    // ---- front: stage tile with all 8 waves. row = tid>>3, slot s0 = tid&7,
    //      granules g = s0 + u*8 (u=0..7); coalesced 256B per 8-thread group.
    {
        const int arow = tid >> 3;
        const int as0  = tid & 7;
        const float* srcrow = x + (size_t)(m0 + arow) * DIM;
        unsigned char* dstrow = ldsA + arow * 1024;
#pragma unroll
        for (int u = 0; u < 8; ++u)
            stage_granule(srcrow, dstrow, as0 + u * 8, arow);
    }
    __syncthreads();                  // the ONLY barrier

    // ---- kloop (R16-proven): dense B streams, depth-3 rotation, pinned
    const bf16x8* bfr = (const bf16x8*)Bf + (size_t)w * 4096 + lane;   // + j*1024 + s*64

    f32x4 acc[4][4] = {};
    bf16x8 b0[4], b1[4], b2[4], af[4];

    auto loadB = [&](int s, bf16x8 (&bb)[4]) {
#pragma unroll
        for (int j = 0; j < 4; ++j)
            bb[j] = bfr[j * 1024 + s * 64];
    };
    auto sliceA = [&](int s) {
#pragma unroll
        for (int i = 0; i < 4; ++i) {
            const int row = i * 16 + lr;
            const int gsl = s * 4 + lg;
            const int sw  = (gsl & ~7) | ((gsl ^ row) & 7);
            af[i] = *(const bf16x8*)(ldsA + row * 1024 + sw * 16);
        }
    };
    auto mf = [&](bf16x8 (&bb)[4]) {
#pragma unroll
        for (int j = 0; j < 4; ++j)
#pragma unroll
            for (int i = 0; i < 4; ++i)
                acc[j][i] = __builtin_amdgcn_mfma_f32_16x16x32_bf16(bb[j], af[i], acc[j][i], 0, 0, 0);
    };

    loadB(0, b0); loadB(1, b1); loadB(2, b2);
#define KSTEP(s, BSET)                                        \
    { sliceA(s); mf(BSET);                                    \
      if ((s) + 3 < 16) loadB((s) + 3, BSET);                 \
      __builtin_amdgcn_sched_barrier(0); }
    KSTEP(0,  b0) KSTEP(1,  b1) KSTEP(2,  b2)
    KSTEP(3,  b0) KSTEP(4,  b1) KSTEP(5,  b2)
    KSTEP(6,  b0) KSTEP(7,  b1) KSTEP(8,  b2)
    KSTEP(9,  b0) KSTEP(10, b1) KSTEP(11, b2)
    KSTEP(12, b0) KSTEP(13, b1) KSTEP(14, b2)
    KSTEP(15, b0)
#undef KSTEP

    // ---- epilogue (proven): token = m0 + i*16 + lr; feats = f0 + j*16 + lg*4
    f32x4 bs4[4];
#pragma unroll
    for (int j = 0; j < 4; ++j)
        bs4[j] = *(const f32x4*)(bsum + f0 + j * 16 + lg * 4);
#pragma unroll
    for (int i = 0; i < 4; ++i) {
        const int row = m0 + i * 16 + lr;
        const float wt = wts[row];
#pragma unroll
        for (int j = 0; j < 4; ++j) {
            f32x4 v;
            v[0] = wt * (acc[j][i][0] + bs4[j][0]);
            v[1] = wt * (acc[j][i][1] + bs4[j][1]);
            v[2] = wt * (acc[j][i][2] + bs4[j][2]);
            v[3] = wt * (acc[j][i][3] + bs4[j][3]);
            *(f32x4*)(out + (size_t)row * DIM + f0 + j * 16 + lg * 4) = v;
        }
    }
}

extern "C" void kernel_launch(void* const* d_in, const int* in_sizes, int n_in,
                              void* d_out, int out_size, void* d_ws, size_t ws_size,
                              hipStream_t stream) {
    const float* x   = (const float*)d_in[0];   // [N, D]
    const float* wts = (const float*)d_in[1];   // [N, 1]
    const float* W   = (const float*)d_in[2];   // [E, D, D]
    const float* b   = (const float*)d_in[3];   // [E, D]
    float* out       = (float*)d_out;           // [N, D]

    unsigned short* Bfrag = (unsigned short*)d_ws;                    // 512 KB bf16
    float*          bsum  = (float*)((char*)d_ws + DIM * DIM * 2);    // 2 KB f32

    moe_prep<<<dim3((DIM * DIM / 8) / 64), dim3(64), 0, stream>>>(W, b, Bfrag, bsum);

    moe_gemm<<<dim3(N_TOK / BM), dim3(512), 0, stream>>>(x, wts, Bfrag, bsum, out);
}

// Round 23
// 43.831 us; speedup vs baseline: 2.4112x; 2.4112x over previous
//
#include <hip/hip_runtime.h>
#include <hip/hip_bf16.h>

// out[n,f] = weights[n] * ( x[n,:] . Wsum[f,:] + bsum[f] )
// Wsum = sum_e W[e], bsum = sum_e b[e]  (expert sum commutes with Linear).
// Wsum stored fragment-major ("Bfrag", R6) -> dense lane-consecutive B streams.
// R22 = R21 with the launch_bounds fix. Empirically on this toolchain the 2nd
// __launch_bounds__ arg acts like CUDA minBlocksPerMultiprocessor:
//   (512,4) -> 32 waves/CU -> VGPR cap 64 (R21: spilled, 105us)
//   (512,2) -> 16 waves/CU -> VGPR cap 128 (R19: 120 VGPR, no spill)
// Single 64-token tile + 64KB LDS -> 2 co-resident blocks/CU: 4 waves/SIMD in
// the kloop (hides ds_read->MFMA latency) + CU-level phase mixing across the
// staggered block pair. Kloop = R16-proven depth-3 pinned B prefetch.

#define N_TOK 32768
#define DIM   512
#define NEXP  8
#define BM    64            // tokens per block (single tile)

typedef __attribute__((ext_vector_type(8))) short  bf16x8;
typedef __attribute__((ext_vector_type(4))) float  f32x4;

__device__ __forceinline__ unsigned int pk2bf(float a, float b) {
    unsigned ua = __float_as_uint(a), ub = __float_as_uint(b);
    ua = (ua + 0x7FFFu + ((ua >> 16) & 1u)) >> 16;   // RNE to bf16
    ub = (ub + 0x7FFFu + ((ub >> 16) & 1u)) >> 16;
    return ua | (ub << 16);
}

// ---------------- prep: Bfrag (bf16, fragment-major) + bsum (f32) ---- (proven) ----
__global__ __launch_bounds__(64) void moe_prep(const float* __restrict__ W,
                                               const float* __restrict__ b,
                                               unsigned short* __restrict__ Bfrag,
                                               float* __restrict__ bsum) {
    const int g = blockIdx.x * 64 + threadIdx.x;     // 0..32767
    const int f = g >> 6;
    const int q = g & 63;
    const float* src = W + (size_t)f * DIM + q * 8;
    float s0 = 0, s1 = 0, s2 = 0, s3 = 0, s4 = 0, s5 = 0, s6 = 0, s7 = 0;
#pragma unroll
    for (int e = 0; e < NEXP; ++e) {
        float4 u0 = *(const float4*)(src + (size_t)e * DIM * DIM);
        float4 u1 = *(const float4*)(src + (size_t)e * DIM * DIM + 4);
        s0 += u0.x; s1 += u0.y; s2 += u0.z; s3 += u0.w;
        s4 += u1.x; s5 += u1.y; s6 += u1.z; s7 += u1.w;
    }
    uint4 v;
    v.x = pk2bf(s0, s1); v.y = pk2bf(s2, s3);
    v.z = pk2bf(s4, s5); v.w = pk2bf(s6, s7);

    const int F  = f >> 6, j = (f >> 4) & 3, lr = f & 15;
    const int sl = q >> 2, lg = q & 3;
    const int idx16 = ((F * 4 + j) * 16 + sl) * 64 + (lg * 16 + lr);
    *(uint4*)(Bfrag + (size_t)idx16 * 8) = v;

    if (g < DIM / 4) {
        float4 bs = make_float4(0.f, 0.f, 0.f, 0.f);
#pragma unroll
        for (int e = 0; e < NEXP; ++e) {
            float4 u = *(const float4*)(b + e * DIM + g * 4);
            bs.x += u.x; bs.y += u.y; bs.z += u.z; bs.w += u.w;
        }
        *(float4*)(bsum + g * 4) = bs;
    }
}

// ---- one granule: 8 f32 -> 16B bf16, XOR-swizzled LDS write (proven pair) ----
__device__ __forceinline__ void stage_granule(const float* __restrict__ srcrow,
                                              unsigned char* __restrict__ dstrow,
                                              int g, int row) {
    float4 u0 = *(const float4*)(srcrow + g * 8);
    float4 u1 = *(const float4*)(srcrow + g * 8 + 4);
    const int sg = (g & ~7) | ((g ^ row) & 7);
    uint4 v;
    v.x = pk2bf(u0.x, u0.y); v.y = pk2bf(u0.z, u0.w);
    v.z = pk2bf(u1.x, u1.y); v.w = pk2bf(u1.z, u1.w);
    *(uint4*)(dstrow + sg * 16) = v;
}

// ---------------- main GEMM: single tile, 2 blocks/CU, depth-3 pinned kloop ----------------
// Grid 512 (2 blocks/CU via 64KB LDS; VGPR cap 128 via launch_bounds(512,2)).
// Wave w owns features [w*64,(w+1)*64).
__global__ __launch_bounds__(512, 2) void moe_gemm(const float* __restrict__ x,
                                                   const float* __restrict__ wts,
                                                   const unsigned short* __restrict__ Bf,
                                                   const float* __restrict__ bsum,
                                                   float* __restrict__ out) {
    __shared__ __align__(16) unsigned char ldsA[BM * DIM * 2];   // 64 KB

    const int tid  = threadIdx.x;
    const int lane = tid & 63;
    const int w    = tid >> 6;       // 0..7
    const int lr   = lane & 15;
    const int lg   = lane >> 4;
    const int m0   = blockIdx.x * BM;
    const int f0   = w * 64;

    // ---- front: stage tile with all 8 waves. row = tid>>3, slot s0 = tid&7,
    //      granules g = s0 + u*8 (u=0..7); coalesced 256B per 8-thread group.
    {
        const int arow = tid >> 3;
        const int as0  = tid & 7;
        const float* srcrow = x + (size_t)(m0 + arow) * DIM;
        unsigned char* dstrow = ldsA + arow * 1024;
#pragma unroll
        for (int u = 0; u < 8; ++u)
            stage_granule(srcrow, dstrow, as0 + u * 8, arow);
    }
    __syncthreads();                  // the ONLY barrier

    // ---- kloop (R16-proven): dense B streams, depth-3 rotation, pinned
    const bf16x8* bfr = (const bf16x8*)Bf + (size_t)w * 4096 + lane;   // + j*1024 + s*64

    f32x4 acc[4][4] = {};
    bf16x8 b0[4], b1[4], b2[4], af[4];

    auto loadB = [&](int s, bf16x8 (&bb)[4]) {
#pragma unroll
        for (int j = 0; j < 4; ++j)
            bb[j] = bfr[j * 1024 + s * 64];
    };
    auto sliceA = [&](int s) {
#pragma unroll
        for (int i = 0; i < 4; ++i) {
            const int row = i * 16 + lr;
            const int gsl = s * 4 + lg;
            const int sw  = (gsl & ~7) | ((gsl ^ row) & 7);
            af[i] = *(const bf16x8*)(ldsA + row * 1024 + sw * 16);
        }
    };
    auto mf = [&](bf16x8 (&bb)[4]) {
#pragma unroll
        for (int j = 0; j < 4; ++j)
#pragma unroll
            for (int i = 0; i < 4; ++i)
                acc[j][i] = __builtin_amdgcn_mfma_f32_16x16x32_bf16(bb[j], af[i], acc[j][i], 0, 0, 0);
    };

    loadB(0, b0); loadB(1, b1); loadB(2, b2);
#define KSTEP(s, BSET)                                        \
    { sliceA(s); mf(BSET);                                    \
      if ((s) + 3 < 16) loadB((s) + 3, BSET);                 \
      __builtin_amdgcn_sched_barrier(0); }
    KSTEP(0,  b0) KSTEP(1,  b1) KSTEP(2,  b2)
    KSTEP(3,  b0) KSTEP(4,  b1) KSTEP(5,  b2)
    KSTEP(6,  b0) KSTEP(7,  b1) KSTEP(8,  b2)
    KSTEP(9,  b0) KSTEP(10, b1) KSTEP(11, b2)
    KSTEP(12, b0) KSTEP(13, b1) KSTEP(14, b2)
    KSTEP(15, b0)
#undef KSTEP

    // ---- epilogue (proven): token = m0 + i*16 + lr; feats = f0 + j*16 + lg*4
    f32x4 bs4[4];
#pragma unroll
    for (int j = 0; j < 4; ++j)
        bs4[j] = *(const f32x4*)(bsum + f0 + j * 16 + lg * 4);
#pragma unroll
    for (int i = 0; i < 4; ++i) {
        const int row = m0 + i * 16 + lr;
        const float wt = wts[row];
#pragma unroll
        for (int j = 0; j < 4; ++j) {
            f32x4 v;
            v[0] = wt * (acc[j][i][0] + bs4[j][0]);
            v[1] = wt * (acc[j][i][1] + bs4[j][1]);
            v[2] = wt * (acc[j][i][2] + bs4[j][2]);
            v[3] = wt * (acc[j][i][3] + bs4[j][3]);
            *(f32x4*)(out + (size_t)row * DIM + f0 + j * 16 + lg * 4) = v;
        }
    }
}

extern "C" void kernel_launch(void* const* d_in, const int* in_sizes, int n_in,
                              void* d_out, int out_size, void* d_ws, size_t ws_size,
                              hipStream_t stream) {
    const float* x   = (const float*)d_in[0];   // [N, D]
    const float* wts = (const float*)d_in[1];   // [N, 1]
    const float* W   = (const float*)d_in[2];   // [E, D, D]
    const float* b   = (const float*)d_in[3];   // [E, D]
    float* out       = (float*)d_out;           // [N, D]

    unsigned short* Bfrag = (unsigned short*)d_ws;                    // 512 KB bf16
    float*          bsum  = (float*)((char*)d_ws + DIM * DIM * 2);    // 2 KB f32

    moe_prep<<<dim3((DIM * DIM / 8) / 64), dim3(64), 0, stream>>>(W, b, Bfrag, bsum);

    moe_gemm<<<dim3(N_TOK / BM), dim3(512), 0, stream>>>(x, wts, Bfrag, bsum, out);
}